// Round 6
// baseline (192.479 us; speedup 1.0000x reference)
//
#include <hip/hip_runtime.h>
#include <hip/hip_fp16.h>

// SSIM loss, fused producer/consumer, small-tile high-parallelism version.
// (16,3,512,512) f32 -> scalar. Box = separable 11-tap mean, zero pad.
// Block = (plane, 64x64 tile), 128 threads = 2 waves:
//   wave 0 (tid 0..63) : H producer — 8 rows/iter x 8 runs x 8 cols -> fp16 ring
//   wave 1 (tid 64..127): V consumer — 1 col each; running vertical sums with
//                         an 11-lag subtraction served from a depth-16 REGISTER
//                         history (static indices via t-parity), so the ring
//                         only needs CAP=17 slots -> 13.5 KB LDS.
// Grid 8x8x48 = 3072 blocks = 6144 waves (24/CU supply); VGPR-capped ~16/CU.

#define CAP   17
#define ROWF  66                 // 64 cols + swizzle pad
#define SSTR  (3 * ROWF)         // 3 dword planes: (q0q1),(q2q3),(q4,-)
#define C1K   1.4641f            // 0.01^2 * 121^2
#define C2K   13.1769f           // 0.03^2 * 121^2

__device__ __forceinline__ int swz(int x) { return x + (x >> 5); }

__launch_bounds__(128, 4)
__global__ void ssim_fused(const float* __restrict__ img1,
                           const float* __restrict__ img2,
                           float* __restrict__ out)
{
    __shared__ unsigned int ring[CAP * SSTR];

    const int x0 = blockIdx.x * 64;
    const int y0 = blockIdx.y * 64;
    const size_t pbase = (size_t)blockIdx.z * (512 * 512);
    const int tid = threadIdx.x;

    const int hj = tid >> 3;            // producer: row in batch (0..7)
    const int hk = tid & 7;             // producer: run index (8 cols each)
    const int xl = x0 + hk * 8 - 8;     // f4-aligned load start
    const int xs = swz(tid & 63);       // consumer: swizzled col

    float S0 = 0.f, S1 = 0.f, S2 = 0.f, S3 = 0.f, S4 = 0.f, accs = 0.f;

    // consumer register history (fp16-packed); static-indexed only.
    unsigned int h[16][3];
#pragma unroll
    for (int q = 0; q < 16; ++q) { h[q][0] = 0u; h[q][1] = 0u; h[q][2] = 0u; }

    int pslot = hj;                     // (8t+hj) % CAP, maintained
    int cbase = 0;                      // slot of rel = 8*(t-1)

    // consumer body: slots compile-time per (parity, jj).
#define CONSUME(ODDQ)                                                          \
    {                                                                          \
        _Pragma("unroll")                                                      \
        for (int jj = 0; jj < 8; ++jj) {                                       \
            const int rel = relbase + jj;                                      \
            if (rel > 73) break;                                               \
            int sa = cbase + jj; if (sa >= CAP) sa -= CAP;                     \
            const unsigned int* ab = &ring[sa * SSTR + xs];                    \
            const unsigned int u01 = ab[0];                                    \
            const unsigned int u23 = ab[ROWF];                                 \
            const unsigned int u4  = ab[2 * ROWF];                             \
            const float2 f01 = __half22float2(*(const __half2*)&u01);          \
            const float2 f23 = __half22float2(*(const __half2*)&u23);          \
            const float2 f4v = __half22float2(*(const __half2*)&u4);           \
            const int ws = (ODDQ) ? jj : 8 + jj;                               \
            const int ss = (ODDQ) ? jj + 5 : ((13 + jj) & 15);                 \
            const unsigned int g01 = h[ss][0], g23 = h[ss][1], g4 = h[ss][2];  \
            const float2 e01 = __half22float2(*(const __half2*)&g01);          \
            const float2 e23 = __half22float2(*(const __half2*)&g23);          \
            const float2 e4v = __half22float2(*(const __half2*)&g4);           \
            S0 += f01.x - e01.x; S1 += f01.y - e01.y;                          \
            S2 += f23.x - e23.x; S3 += f23.y - e23.y;                          \
            S4 += f4v.x - e4v.x;                                               \
            h[ws][0] = u01; h[ws][1] = u23; h[ws][2] = u4;                     \
            if (rel >= 10) {                                                   \
                const float t01 = S0 * S1;                                     \
                const float p0  = S0 * S0, p1 = S1 * S1;                       \
                const float num = (2.f * t01 + C1K)                            \
                                * (2.f * (121.f * S4 - t01) + C2K);            \
                const float den = (p0 + p1 + C1K)                              \
                                * (121.f * (S2 + S3) - p0 - p1 + C2K);         \
                accs += num * __builtin_amdgcn_rcpf(den);                      \
            }                                                                  \
        }                                                                      \
    }

    for (int t = 0; t <= 10; ++t) {
        if (tid < 64) {
            // ---------------- producer: batch t (rels 8t..8t+7) -------------
            if (t <= 9) {
                const int rel = 8 * t + hj;
                if (rel <= 73) {
                    const int r = y0 - 5 + rel;
                    float a[24], b[24];
                    if ((unsigned)r < 512u) {
                        const float* p1 = img1 + pbase + (size_t)r * 512;
                        const float* p2 = img2 + pbase + (size_t)r * 512;
#pragma unroll
                        for (int u = 0; u < 6; ++u) {
                            const int c4 = xl + 4 * u;
                            float4 v1 = {0.f, 0.f, 0.f, 0.f};
                            float4 v2 = {0.f, 0.f, 0.f, 0.f};
                            if ((unsigned)c4 < 512u) {
                                v1 = *(const float4*)(p1 + c4);
                                v2 = *(const float4*)(p2 + c4);
                            }
                            a[4*u] = v1.x; a[4*u+1] = v1.y; a[4*u+2] = v1.z; a[4*u+3] = v1.w;
                            b[4*u] = v2.x; b[4*u+1] = v2.y; b[4*u+2] = v2.z; b[4*u+3] = v2.w;
                        }
                    } else {
#pragma unroll
                        for (int u = 0; u < 24; ++u) { a[u] = 0.f; b[u] = 0.f; }
                    }

                    // initial 11-window: output col hk*8 covers a[3..13]
                    float w0 = 0.f, w1 = 0.f, w2 = 0.f, w3 = 0.f, w4 = 0.f;
#pragma unroll
                    for (int c = 0; c < 11; ++c) {
                        const float av = a[c + 3], bv = b[c + 3];
                        w0 += av; w1 += bv; w2 += av * av; w3 += bv * bv; w4 += av * bv;
                    }

                    unsigned int* rb = &ring[pslot * SSTR];
#pragma unroll
                    for (int i = 0; i < 8; ++i) {
                        const int ad = swz(hk * 8 + i);
                        const __half2 h01 = __floats2half2_rn(w0, w1);
                        const __half2 h23 = __floats2half2_rn(w2, w3);
                        const __half2 h4x = __floats2half2_rn(w4, 0.f);
                        rb[ad]            = *(const unsigned int*)&h01;
                        rb[ad + ROWF]     = *(const unsigned int*)&h23;
                        rb[ad + 2 * ROWF] = *(const unsigned int*)&h4x;
                        if (i < 7) {   // slide: add a[14+i], drop a[3+i]
                            const float aN = a[14 + i], aO = a[3 + i];
                            const float bN = b[14 + i], bO = b[3 + i];
                            w0 += aN - aO;
                            w1 += bN - bO;
                            w2 += aN * aN - aO * aO;
                            w3 += bN * bN - bO * bO;
                            w4 += aN * bN - aO * bO;
                        }
                    }
                }
                pslot += 8; if (pslot >= CAP) pslot -= CAP;
            }
        } else {
            // ---------------- consumer: batch t-1 (rels 8(t-1)..+7) ---------
            if (t >= 1) {
                const int relbase = 8 * (t - 1);
                if (t & 1) CONSUME(1) else CONSUME(0)
                cbase += 8; if (cbase >= CAP) cbase -= CAP;
            }
        }
        __syncthreads();
    }
#undef CONSUME

    // ---------------- block reduction + global atomic ----------------
    float tot = accs;
#pragma unroll
    for (int off = 32; off > 0; off >>= 1)
        tot += __shfl_down(tot, off);
    float* red = (float*)ring;
    if ((tid & 63) == 0) red[tid >> 6] = tot;
    __syncthreads();
    if (tid == 0) {
        const float s = red[0] + red[1];
        atomicAdd(out, 1.0f / 3072.0f - s * (1.0f / 12582912.0f));
    }
}

extern "C" void kernel_launch(void* const* d_in, const int* in_sizes, int n_in,
                              void* d_out, int out_size, void* d_ws, size_t ws_size,
                              hipStream_t stream)
{
    const float* img1 = (const float*)d_in[0];
    const float* img2 = (const float*)d_in[1];
    float* out = (float*)d_out;

    hipMemsetAsync(out, 0, sizeof(float), stream);

    dim3 grid(8, 8, 48);
    ssim_fused<<<grid, dim3(128), 0, stream>>>(img1, img2, out);
}

// Round 11
// 176.412 us; speedup vs baseline: 1.0911x; 1.0911x over previous
//
#include <hip/hip_runtime.h>
#include <hip/hip_fp16.h>

// SSIM loss, fused producer/consumer.
// (16,3,512,512) f32 -> scalar. Box = separable 11-tap mean, zero pad.
// Block = (plane, 128x64 tile), 256 threads = 4 waves:
//   tid 0..127  : H producer — 8 rows/batch x 16 runs x 8 cols -> fp16 ring
//   tid 128..255: V consumer — 1 col each; running vertical sums; the 11-lag
//                 subtraction is served from a depth-16 REGISTER history with
//                 compile-time indices (parity-specialized, NO break in the
//                 unrolled loop -> no scratch spill, unlike round 6).
// Ring: CAP=16 slots x 3 dword planes x 134 cols = 25.7 KB LDS.
//   slot stride 402 = 18 (mod 32) -> producer stores <=2-way, reads 2-way (free).
// Grid 4x8x48 = 1536 blocks = 6 blocks/CU; launch_bounds(256,4) => 16 waves/CU
// supply without spill pressure (est ~116 VGPR < 128 budget).

#define CAP   16
#define ROWF  134                // 128 cols + swz pad (max swz(127)=130) + bank tune
#define SSTR  (3 * ROWF)         // 402 dwords per slot
#define C1K   1.4641f            // 0.01^2 * 121^2
#define C2K   13.1769f           // 0.03^2 * 121^2

__device__ __forceinline__ int swz(int x) { return x + (x >> 5); }

__launch_bounds__(256, 4)
__global__ void ssim_fused(const float* __restrict__ img1,
                           const float* __restrict__ img2,
                           float* __restrict__ out)
{
    __shared__ unsigned int ring[CAP * SSTR];   // 25728 B

    const int x0 = blockIdx.x * 128;
    const int y0 = blockIdx.y * 64;
    const size_t pbase = (size_t)blockIdx.z * (512 * 512);
    const int tid = threadIdx.x;

    const int hj = (tid & 127) >> 4;    // producer: row in batch (0..7)
    const int hk = tid & 15;            // producer: run index (8 cols each)
    const int xl = x0 + hk * 8 - 8;     // f4-aligned load start
    const int xs = swz(tid & 127);      // consumer: swizzled col

    float S0 = 0.f, S1 = 0.f, S2 = 0.f, S3 = 0.f, S4 = 0.f, accs = 0.f;

    // consumer register history; ONLY compile-time indices touch it.
    unsigned int h[16][3];
#pragma unroll
    for (int q = 0; q < 16; ++q) { h[q][0] = 0u; h[q][1] = 0u; h[q][2] = 0u; }

    // Q = (t-1)&1. Slot of rel = relbase+jj is Q*8+jj (static).
    // History write slot ws = rel&15 = Q*8+jj; subtract slot ss = (rel-11)&15.
#define CONSUME(Q)                                                             \
    {                                                                          \
        _Pragma("unroll")                                                      \
        for (int jj = 0; jj < 8; ++jj) {                                       \
            const int rel = relbase + jj;                                      \
            if (rel <= 73) {   /* uniform guard, unroll-safe */                \
                const unsigned int* ab = &ring[((Q) * 8 + jj) * SSTR + xs];    \
                const unsigned int u01 = ab[0];                                \
                const unsigned int u23 = ab[ROWF];                             \
                const unsigned int u4  = ab[2 * ROWF];                         \
                const float2 f01 = __half22float2(*(const __half2*)&u01);      \
                const float2 f23 = __half22float2(*(const __half2*)&u23);      \
                const float2 f4v = __half22float2(*(const __half2*)&u4);       \
                const int ws = (Q) * 8 + jj;                                   \
                const int ss = (Q) ? (jj < 3 ? jj + 13 : jj - 3) : jj + 5;     \
                const unsigned int g01 = h[ss][0];                             \
                const unsigned int g23 = h[ss][1];                             \
                const unsigned int g4  = h[ss][2];                             \
                const float2 e01 = __half22float2(*(const __half2*)&g01);      \
                const float2 e23 = __half22float2(*(const __half2*)&g23);      \
                const float2 e4v = __half22float2(*(const __half2*)&g4);       \
                S0 += f01.x - e01.x; S1 += f01.y - e01.y;                      \
                S2 += f23.x - e23.x; S3 += f23.y - e23.y;                      \
                S4 += f4v.x - e4v.x;                                           \
                h[ws][0] = u01; h[ws][1] = u23; h[ws][2] = u4;                 \
                if (rel >= 10) {                                               \
                    const float t01 = S0 * S1;                                 \
                    const float p0  = S0 * S0, p1 = S1 * S1;                   \
                    const float num = (2.f * t01 + C1K)                        \
                                    * (2.f * (121.f * S4 - t01) + C2K);        \
                    const float den = (p0 + p1 + C1K)                          \
                                    * (121.f * (S2 + S3) - p0 - p1 + C2K);     \
                    accs += num * __builtin_amdgcn_rcpf(den);                  \
                }                                                              \
            }                                                                  \
        }                                                                      \
    }

    for (int t = 0; t <= 10; ++t) {
        if (tid < 128) {
            // ---------------- producer: batch t (rels 8t..8t+7) -------------
            if (t <= 9) {
                const int rel = 8 * t + hj;
                if (rel <= 73) {
                    const int r = y0 - 5 + rel;
                    float a[24], b[24];
                    if ((unsigned)r < 512u) {
                        const float* p1 = img1 + pbase + (size_t)r * 512;
                        const float* p2 = img2 + pbase + (size_t)r * 512;
#pragma unroll
                        for (int u = 0; u < 6; ++u) {
                            const int c4 = xl + 4 * u;
                            float4 v1 = {0.f, 0.f, 0.f, 0.f};
                            float4 v2 = {0.f, 0.f, 0.f, 0.f};
                            if ((unsigned)c4 < 512u) {
                                v1 = *(const float4*)(p1 + c4);
                                v2 = *(const float4*)(p2 + c4);
                            }
                            a[4*u] = v1.x; a[4*u+1] = v1.y; a[4*u+2] = v1.z; a[4*u+3] = v1.w;
                            b[4*u] = v2.x; b[4*u+1] = v2.y; b[4*u+2] = v2.z; b[4*u+3] = v2.w;
                        }
                    } else {
#pragma unroll
                        for (int u = 0; u < 24; ++u) { a[u] = 0.f; b[u] = 0.f; }
                    }

                    // initial 11-window: output col hk*8 covers a[3..13]
                    float w0 = 0.f, w1 = 0.f, w2 = 0.f, w3 = 0.f, w4 = 0.f;
#pragma unroll
                    for (int c = 0; c < 11; ++c) {
                        const float av = a[c + 3], bv = b[c + 3];
                        w0 += av; w1 += bv; w2 += av * av; w3 += bv * bv; w4 += av * bv;
                    }

                    unsigned int* rb = &ring[(rel & 15) * SSTR];
#pragma unroll
                    for (int i = 0; i < 8; ++i) {
                        const int ad = swz(hk * 8 + i);
                        const __half2 h01 = __floats2half2_rn(w0, w1);
                        const __half2 h23 = __floats2half2_rn(w2, w3);
                        const __half2 h4x = __floats2half2_rn(w4, 0.f);
                        rb[ad]            = *(const unsigned int*)&h01;
                        rb[ad + ROWF]     = *(const unsigned int*)&h23;
                        rb[ad + 2 * ROWF] = *(const unsigned int*)&h4x;
                        if (i < 7) {   // slide: add a[14+i], drop a[3+i]
                            const float aN = a[14 + i], aO = a[3 + i];
                            const float bN = b[14 + i], bO = b[3 + i];
                            w0 += aN - aO;
                            w1 += bN - bO;
                            w2 += aN * aN - aO * aO;
                            w3 += bN * bN - bO * bO;
                            w4 += aN * bN - aO * bO;
                        }
                    }
                }
            }
        } else {
            // ---------------- consumer: batch t-1 (rels 8(t-1)..+7) ---------
            if (t >= 1) {
                const int relbase = 8 * (t - 1);
                if ((t - 1) & 1) CONSUME(1) else CONSUME(0)
            }
        }
        __syncthreads();
    }
#undef CONSUME

    // ---------------- block reduction + global atomic ----------------
    float tot = accs;
#pragma unroll
    for (int off = 32; off > 0; off >>= 1)
        tot += __shfl_down(tot, off);
    float* red = (float*)ring;
    if ((tid & 63) == 0) red[tid >> 6] = tot;
    __syncthreads();
    if (tid == 0) {
        const float s = red[0] + red[1] + red[2] + red[3];
        atomicAdd(out, 1.0f / 1536.0f - s * (1.0f / 12582912.0f));
    }
}

extern "C" void kernel_launch(void* const* d_in, const int* in_sizes, int n_in,
                              void* d_out, int out_size, void* d_ws, size_t ws_size,
                              hipStream_t stream)
{
    const float* img1 = (const float*)d_in[0];
    const float* img2 = (const float*)d_in[1];
    float* out = (float*)d_out;

    hipMemsetAsync(out, 0, sizeof(float), stream);

    dim3 grid(4, 8, 48);
    ssim_fused<<<grid, dim3(256), 0, stream>>>(img1, img2, out);
}